// Round 4
// baseline (205.054 us; speedup 1.0000x reference)
//
#include <hip/hip_runtime.h>

#define B_  8
#define C_  128
#define H_  96
#define W_  160
#define HWp (H_ * W_)   // 15360 = one channel plane
#define PADY 4
#define HP  104         // H_ + 2*PADY
#define WP  176         // W_ + 16: halo (+8) plus slack so the 32-wide DMA window never goes OOB

typedef short  short8  __attribute__((ext_vector_type(8)));
typedef float  floatx4 __attribute__((ext_vector_type(4)));

// round-to-nearest-even fp32 -> bf16, packed pair (a low 16, b high 16)
__device__ __forceinline__ unsigned pk_bf16(float a, float b) {
    unsigned ua = __float_as_uint(a);
    unsigned ub = __float_as_uint(b);
    ua = (ua + 0x7FFFu + ((ua >> 16) & 1u)) >> 16;
    ub = (ub + 0x7FFFu + ((ub >> 16) & 1u)) & 0xFFFF0000u;
    return ua | ub;
}

// async 16B-per-lane global->LDS DMA (offset arg must be a literal constant,
// so chunk offsets are folded into the global pointer at the call site).
__device__ __forceinline__ void gload_lds16(const void* g, void* l) {
    __builtin_amdgcn_global_load_lds(
        (const __attribute__((address_space(1))) unsigned int*)g,
        (__attribute__((address_space(3))) unsigned int*)l, 16, 0, 0);
}

// ---------------------------------------------------------------------------
// Prep v2: fp32 NCHW -> bf16 NHWC, LDS-free direct transpose.
// Block = one output row (640 threads = 10 waves). Thread (x, cq) reads 32
// consecutive channels at its x (32 coalesced b32 loads: lanes sweep x ->
// 64B segments per c-plane), packs pairs in-register, stores 4 x uint4
// straight into NHWC (L2 write-combines the 16B record stores into full
// lines). Zero barriers, zero LDS, 32-deep per-thread memory ILP.
//   id < 832 : two[b][c][y][x] -> two_t[b][y+4][x+4][c]  (zero-padded halo)
//   id >=832 : one[b][c][y][x] -> one_t[b][y][x][c]
// ---------------------------------------------------------------------------
__global__ void prep_kernel(const float* __restrict__ two, const float* __restrict__ one,
                            unsigned short* __restrict__ two_t,
                            unsigned short* __restrict__ one_t) {
    const int id  = blockIdx.x;
    const int tid = threadIdx.x;
    const uint4 z{0u, 0u, 0u, 0u};

    if (id < 832) {
        // ----- two path: padded rows -----
        const int b    = id & 7;             // batch spread across XCDs
        const int ypad = id >> 3;            // 0..103
        unsigned short* rowdst = two_t + (size_t)(b * HP + ypad) * WP * C_;

        if (ypad < PADY || ypad >= PADY + H_) {
            // border row: zero all 176*16 records
            #pragma unroll
            for (int i = 0; i < 5; ++i) {
                const int g = tid + i * 640;
                if (g < WP * 16) {
                    const int x = g >> 4, r = g & 15;
                    *reinterpret_cast<uint4*>(rowdst + (size_t)x * C_ + r * 8) = z;
                }
            }
            return;
        }

        const int y = ypad - PADY;
        // x-halo zeros: 16 halo columns * 16 records = 256 units
        if (tid < 256) {
            const int hx = tid >> 4, r = tid & 15;
            const int xp = (hx < 4) ? hx : hx + 160;     // {0..3, 164..175}
            *reinterpret_cast<uint4*>(rowdst + (size_t)xp * C_ + r * 8) = z;
        }

        // main: thread = (x = tid>>2, cq = tid&3); 640 threads cover 160x * 4cq
        const int x  = tid >> 2;
        const int cq = tid & 3;
        const float* src = two + ((size_t)(b * C_ + cq * 32) * H_ + y) * W_ + x;
        float v[32];
        #pragma unroll
        for (int j = 0; j < 32; ++j) v[j] = src[(size_t)j * HWp];
        unsigned short* d = rowdst + (size_t)(x + 4) * C_ + cq * 32;
        #pragma unroll
        for (int rr = 0; rr < 4; ++rr) {
            uint4 u;
            u.x = pk_bf16(v[rr * 8 + 0], v[rr * 8 + 1]);
            u.y = pk_bf16(v[rr * 8 + 2], v[rr * 8 + 3]);
            u.z = pk_bf16(v[rr * 8 + 4], v[rr * 8 + 5]);
            u.w = pk_bf16(v[rr * 8 + 6], v[rr * 8 + 7]);
            *reinterpret_cast<uint4*>(d + rr * 8) = u;
        }
    } else {
        // ----- one path: no padding -----
        const int g2 = id - 832;
        const int b  = g2 & 7;
        const int y  = g2 >> 3;              // 0..95
        unsigned short* rowdst = one_t + (size_t)(b * H_ + y) * W_ * C_;

        const int x  = tid >> 2;
        const int cq = tid & 3;
        const float* src = one + ((size_t)(b * C_ + cq * 32) * H_ + y) * W_ + x;
        float v[32];
        #pragma unroll
        for (int j = 0; j < 32; ++j) v[j] = src[(size_t)j * HWp];
        unsigned short* d = rowdst + (size_t)x * C_ + cq * 32;
        #pragma unroll
        for (int rr = 0; rr < 4; ++rr) {
            uint4 u;
            u.x = pk_bf16(v[rr * 8 + 0], v[rr * 8 + 1]);
            u.y = pk_bf16(v[rr * 8 + 2], v[rr * 8 + 3]);
            u.z = pk_bf16(v[rr * 8 + 4], v[rr * 8 + 5]);
            u.w = pk_bf16(v[rr * 8 + 6], v[rr * 8 + 7]);
            *reinterpret_cast<uint4*>(d + rr * 8) = u;
        }
    }
}

// ---------------------------------------------------------------------------
// Pass 2: band-GEMM correlation, pure-DMA staging (both operands via
// global_load_lds from bf16 NHWC), counted vmcnt, raw barriers, coalesced
// LDS-staged epilogue. No register staging, no pack VALU in the loop.
// (unchanged from round 3 — harness-verified)
// ---------------------------------------------------------------------------
__global__ __launch_bounds__(512, 4)
void corr2_kernel(const unsigned short* __restrict__ one_t,
                  const unsigned short* __restrict__ two_t,
                  float* __restrict__ out) {
    __shared__ uint4 two_q[2][16 * 128];   // 32 KB x2: [ry16][ct2*64 + kg4*16 + n16]
    __shared__ uint4 one_q[2][8 * 64];     //  8 KB x2: [y8][kg4*16 + x16]  -> 80 KB total

    const int id = blockIdx.x;
    const int b  = id & 7;            // one batch per XCD
    const int jj = id >> 3;           // 0..119
    const int yt = jj % 12;
    const int xt = jj / 12;
    const int y0 = yt * 8;
    const int x0 = xt * 16;

    const int tid  = threadIdx.x;
    const int lane = tid & 63;
    const int w    = tid >> 6;        // wave id = y-row within tile
    const int kq   = lane >> 4;       // 0..3
    const int nn   = lane & 15;

    // ---- DMA source pointers (per-lane) ----
    const unsigned short* p_one =
        one_t + ((size_t)((b * H_ + y0 + w) * W_ + x0 + nn)) * C_ + kq * 8;
    const unsigned short* p_two[4];
    #pragma unroll
    for (int q = 0; q < 4; ++q) {
        const int ii = w * 4 + q;
        const int ry = ii >> 1, ct = ii & 1;
        p_two[q] = two_t + ((size_t)((b * HP + y0 + ry) * WP + x0 + ct * 16 + nn)) * C_ + kq * 8;
    }

    #define ISSUE(ck, buf) do {                                                  \
        gload_lds16(p_one + (ck) * 32, &one_q[buf][w * 64]);                     \
        _Pragma("unroll")                                                        \
        for (int q = 0; q < 4; ++q)                                              \
            gload_lds16(p_two[q] + (ck) * 32, &two_q[buf][(w * 4 + q) * 64]);    \
    } while (0)

    // raw barrier: drain own LDS ops, do NOT drain vmcnt (DMA stays in flight)
    #define BAR() asm volatile("s_waitcnt lgkmcnt(0)\n\ts_barrier" ::: "memory")

    floatx4 acc[9][2];
    #pragma unroll
    for (int dy = 0; dy < 9; ++dy) {
        acc[dy][0] = floatx4{0.f, 0.f, 0.f, 0.f};
        acc[dy][1] = floatx4{0.f, 0.f, 0.f, 0.f};
    }

    // ---- prologue: 2 chunks in flight (5 vmem ops each) ----
    ISSUE(0, 0);
    ISSUE(1, 1);

    #pragma unroll
    for (int ck = 0; ck < 4; ++ck) {
        const int cur = ck & 1;
        if (ck < 3) asm volatile("s_waitcnt vmcnt(5)" ::: "memory");
        else        asm volatile("s_waitcnt vmcnt(0)" ::: "memory");
        BAR();   // all waves' DMAs for chunk ck have landed -> safe to read

        const short8 A = *reinterpret_cast<const short8*>(&one_q[cur][w * 64 + lane]);
        #pragma unroll
        for (int dy = 0; dy < 9; ++dy) {
            const int ry = w + dy;
            const short8 Bt0 = *reinterpret_cast<const short8*>(&two_q[cur][ry * 128 + lane]);
            const short8 Bt1 = *reinterpret_cast<const short8*>(&two_q[cur][ry * 128 + 64 + lane]);
            acc[dy][0] = __builtin_amdgcn_mfma_f32_16x16x32_bf16(A, Bt0, acc[dy][0], 0, 0, 0);
            acc[dy][1] = __builtin_amdgcn_mfma_f32_16x16x32_bf16(A, Bt1, acc[dy][1], 0, 0, 0);
        }
        BAR();   // all reads of buf[cur] complete before anyone refills it

        if (ck < 2) ISSUE(ck + 2, cur);
    }

    // ---- epilogue: stage into LDS (overlaid on dead two_q), store coalesced ----
    __syncthreads();                               // everyone done with two_q
    float* ep = reinterpret_cast<float*>(&two_q[0][0]);   // 81*130*4 = 42 KB < 64 KB
    const float scale = 1.0f / (float)C_;
    #pragma unroll
    for (int dy = 0; dy < 9; ++dy) {
        #pragma unroll
        for (int ct = 0; ct < 2; ++ct) {
            floatx4 v = acc[dy][ct];
            #pragma unroll
            for (int r = 0; r < 4; ++r) {
                const int m  = kq * 4 + r;
                const int dx = nn - m + ct * 16;
                if ((unsigned)dx <= 8u)
                    ep[(dy * 9 + dx) * 130 + w * 16 + m] = v[r] * scale;
            }
        }
    }
    __syncthreads();
    // 81 planes * 128 floats = 10368 dwords; lanes cover x fastest -> full 64B lines
    #pragma unroll
    for (int i = 0; i < 21; ++i) {
        const int g = tid + i * 512;
        if (g < 81 * 128) {
            const int p   = g >> 7;
            const int loc = g & 127;               // yy*16 + xx
            const int yy  = loc >> 4, xx = loc & 15;
            out[((size_t)(b * 81 + p) * H_ + y0 + yy) * W_ + x0 + xx] = ep[p * 130 + loc];
        }
    }
    #undef ISSUE
    #undef BAR
}

// ---------------------------------------------------------------------------
// Fallback: harness-verified single-pass kernel (used if workspace too small)
// ---------------------------------------------------------------------------
__global__ __launch_bounds__(512, 2)
void corr_kernel(const float* __restrict__ one, const float* __restrict__ two,
                 float* __restrict__ out) {
    __shared__ uint4 one_q[2][8 * 64];
    __shared__ uint4 two_q[2][16 * 128];

    const int id = blockIdx.x;
    const int b  = id & 7;
    const int jj = id >> 3;
    const int yt = jj % 12;
    const int xt = jj / 12;
    const int y0 = yt * 8;
    const int x0 = xt * 16;

    const int tid  = threadIdx.x;
    const int lane = tid & 63;
    const int w    = tid >> 6;

    const int o_xl  = tid & 15;
    const int o_yl  = (tid >> 4) & 7;
    const int o_kg  = tid >> 7;
    const int o_rec = o_yl * 64 + o_kg * 16 + o_xl;

    const int t_cx  = tid & 31;
    const int t_ry  = tid >> 5;
    const int t_y   = y0 - 4 + t_ry;
    const int t_gx  = x0 - 4 + t_cx;
    const bool t_valid = ((unsigned)t_y < H_) && ((unsigned)t_gx < W_) && (t_cx < 24);
    const int t_rec = t_ry * 128 + (t_cx >> 4) * 64 + (t_cx & 15);

    const float* o_base = one + ((size_t)(b * C_ + 8 * o_kg) * H_ + (y0 + o_yl)) * W_ + (x0 + o_xl);
    const float* t_base = two + ((size_t)(b * C_) * H_ + t_y) * W_ + t_gx;

    float ro[8];
    float rt[32];

    floatx4 acc[9][2];
    #pragma unroll
    for (int dy = 0; dy < 9; ++dy) {
        acc[dy][0] = floatx4{0.f, 0.f, 0.f, 0.f};
        acc[dy][1] = floatx4{0.f, 0.f, 0.f, 0.f};
    }

    {
        const float* p1 = o_base;
        #pragma unroll
        for (int i = 0; i < 8; ++i) ro[i] = p1[(size_t)i * HWp];
        if (t_valid) {
            const float* p2 = t_base;
            #pragma unroll
            for (int i = 0; i < 32; ++i) rt[i] = p2[(size_t)i * HWp];
        } else {
            #pragma unroll
            for (int i = 0; i < 32; ++i) rt[i] = 0.f;
        }
    }

    #pragma unroll
    for (int ck = 0; ck < 4; ++ck) {
        const int bf = ck & 1;
        {
            uint4 v;
            v.x = pk_bf16(ro[0], ro[1]);
            v.y = pk_bf16(ro[2], ro[3]);
            v.z = pk_bf16(ro[4], ro[5]);
            v.w = pk_bf16(ro[6], ro[7]);
            one_q[bf][o_rec] = v;
            #pragma unroll
            for (int kg = 0; kg < 4; ++kg) {
                uint4 u;
                u.x = pk_bf16(rt[kg * 8 + 0], rt[kg * 8 + 1]);
                u.y = pk_bf16(rt[kg * 8 + 2], rt[kg * 8 + 3]);
                u.z = pk_bf16(rt[kg * 8 + 4], rt[kg * 8 + 5]);
                u.w = pk_bf16(rt[kg * 8 + 6], rt[kg * 8 + 7]);
                two_q[bf][t_rec + kg * 16] = u;
            }
        }
        __syncthreads();

        if (ck < 3) {
            const float* p1 = o_base + (size_t)((ck + 1) * 32) * HWp;
            #pragma unroll
            for (int i = 0; i < 8; ++i) ro[i] = p1[(size_t)i * HWp];
            if (t_valid) {
                const float* p2 = t_base + (size_t)((ck + 1) * 32) * HWp;
                #pragma unroll
                for (int i = 0; i < 32; ++i) rt[i] = p2[(size_t)i * HWp];
            }
        }

        const short8 A = *reinterpret_cast<const short8*>(&one_q[bf][w * 64 + lane]);
        #pragma unroll
        for (int dy = 0; dy < 9; ++dy) {
            const int ry = w + dy;
            const short8 Bt0 = *reinterpret_cast<const short8*>(&two_q[bf][ry * 128 + lane]);
            const short8 Bt1 = *reinterpret_cast<const short8*>(&two_q[bf][ry * 128 + 64 + lane]);
            acc[dy][0] = __builtin_amdgcn_mfma_f32_16x16x32_bf16(A, Bt0, acc[dy][0], 0, 0, 0);
            acc[dy][1] = __builtin_amdgcn_mfma_f32_16x16x32_bf16(A, Bt1, acc[dy][1], 0, 0, 0);
        }
    }

    const int  qq = lane >> 4;
    const int  nn2 = lane & 15;
    const int  y  = y0 + w;
    const float scale = 1.0f / (float)C_;
    #pragma unroll
    for (int dy = 0; dy < 9; ++dy) {
        #pragma unroll
        for (int ct = 0; ct < 2; ++ct) {
            floatx4 v = acc[dy][ct];
            #pragma unroll
            for (int r = 0; r < 4; ++r) {
                int m  = qq * 4 + r;
                int dx = nn2 - m + ct * 16;
                if ((unsigned)dx <= 8u) {
                    size_t o = ((size_t)(b * 81 + dy * 9 + dx) * H_ + y) * W_ + (x0 + m);
                    out[o] = v[r] * scale;
                }
            }
        }
    }
}

extern "C" void kernel_launch(void* const* d_in, const int* in_sizes, int n_in,
                              void* d_out, int out_size, void* d_ws, size_t ws_size,
                              hipStream_t stream) {
    const float* one = (const float*)d_in[0];
    const float* two = (const float*)d_in[1];
    float* out = (float*)d_out;
    const size_t need_two = (size_t)B_ * HP * WP * C_ * 2;            // 37,486,592 B
    const size_t need_one = (size_t)B_ * H_ * W_ * C_ * 2;            // 31,457,280 B
    if (d_ws != nullptr && ws_size >= need_two + need_one) {
        unsigned short* two_t = (unsigned short*)d_ws;
        unsigned short* one_t = two_t + (size_t)B_ * HP * WP * C_;
        // prep: 832 two-rows + 768 one-rows; 640 threads = one row each
        prep_kernel<<<dim3(1600), dim3(640), 0, stream>>>(two, one, two_t, one_t);
        // corr2: 8 batches * 12 y-tiles * 10 x-tiles = 960 blocks
        corr2_kernel<<<dim3(960), dim3(512), 0, stream>>>(one_t, two_t, out);
    } else {
        corr_kernel<<<dim3(960), dim3(512), 0, stream>>>(one, two, out);
    }
}